// Round 19
// baseline (77.814 us; speedup 1.0000x reference)
//
#include <hip/hip_runtime.h>
#include <stdint.h>

// ---- problem constants ----
constexpr int NB   = 4;      // batch
constexpr int CIN  = 3;
constexpr int HIN  = 256;
constexpr int COUT = 256;
constexpr int HF   = 128;              // feature H=W after stride-2 conv
constexpr int NF   = HF * HF;          // 16384
constexpr int KADM = 16;
constexpr int KK   = KADM * KADM;      // 256 descriptors
constexpr int HID  = 128;              // MLP hidden
constexpr int DFB  = 65536;            // desc-fragment u16s per batch
constexpr int PX   = 64;               // pixels per fused block
constexpr int NT   = NF / PX;          // 256 tiles per batch

typedef unsigned short ushort_t;
typedef __attribute__((ext_vector_type(8))) _Float16 f16x8;
typedef __attribute__((ext_vector_type(2))) __fp16   fp16v2;   // cvt_pkrtz result type
typedef __attribute__((ext_vector_type(4))) float    f32x4;

__device__ inline ushort_t f16bits(_Float16 h) { return __builtin_bit_cast(ushort_t, h); }

__device__ inline unsigned long long shfl_xor_u64(unsigned long long v, int m) {
    unsigned lo = __shfl_xor((unsigned)v, m, 64);
    unsigned hi = __shfl_xor((unsigned)(v >> 32), m, 64);
    return ((unsigned long long)hi << 32) | lo;
}

// LDS swizzle for [PX][256] f16 planes: XOR 8-f16 chunk index with pix&7.
__device__ inline int swz(int pix, int c) {
    return pix * 256 + ((((c >> 3) ^ (pix & 7)) << 3) | (c & 7));
}

// desc/weight fragment address: [kt][chunk][lane][8], kt = k>>4 (16 k-tiles)
__device__ inline int dfoff(int kt, int chunk, int lane) {
    return ((kt * 8 + chunk) * 64 + lane) * 8;
}

// =====================================================================
// Prep: split conv weights into f16 hi/lo (fragment order) + clear
// packed (+inf keys), pooled (0 keys), and the done counter.
// =====================================================================
__global__ __launch_bounds__(256) void prep_kernel(
        const float* __restrict__ W, ushort_t* __restrict__ WFh, ushort_t* __restrict__ WFl,
        unsigned long long* __restrict__ packed, unsigned long long* __restrict__ pooled,
        unsigned* __restrict__ done)
{
    int co = threadIdx.x;
    int kt = co >> 4, la = co & 15;
    #pragma unroll
    for (int q = 0; q < 32; ++q) {
        float v = (q < 27) ? W[co * 27 + q] : 0.f;
        _Float16 h = (_Float16)v;
        _Float16 l = (_Float16)(v - (float)h);
        int lg = q >> 3, e = q & 7;
        int off = (kt * 64 + lg * 16 + la) * 8 + e;
        WFh[off] = f16bits(h);
        WFl[off] = f16bits(l);
    }
    #pragma unroll
    for (int m = 0; m < NB * KK / 256; ++m) {
        packed[m * 256 + co] = ~0ull;
        pooled[m * 256 + co] = 0ull;
    }
    if (co == 0) *done = 0u;
}

// =====================================================================
// Conv-A: MFMA im2col conv + FUSED adaptive-pool argmax.
// =====================================================================
__global__ __launch_bounds__(256) void convA_kernel(
        const float* __restrict__ xA,
        const ushort_t* __restrict__ WFh, const ushort_t* __restrict__ WFl,
        const float* __restrict__ bias, unsigned long long* __restrict__ pooled)
{
    __shared__ float    pS[CIN][3][132];
    __shared__ ushort_t Ah[64][40];
    __shared__ ushort_t Al[64][40];
    __shared__ float    redS[4][64];

    int tile = blockIdx.x;
    int b    = blockIdx.y;
    int oh   = tile >> 1;
    int ow0  = (tile & 1) << 6;
    const float* x = xA + (size_t)b * CIN * HIN * HIN;
    int tid = threadIdx.x;

    for (int i = tid; i < CIN * 3 * 129; i += 256) {
        int ci = i / (3 * 129);
        int r2 = i % (3 * 129);
        int kh = r2 / 129, c = r2 % 129;
        int gr = 2 * oh - 1 + kh, gc = 2 * ow0 - 1 + c;
        float v = 0.f;
        if (gr >= 0 && gr < HIN && gc >= 0 && gc < HIN)
            v = x[(size_t)ci * HIN * HIN + (size_t)gr * HIN + gc];
        pS[ci][kh][c] = v;
    }
    __syncthreads();

    {
        int n = tid >> 2, qg = tid & 3;
        unsigned uh[4], ul[4];
        #pragma unroll
        for (int e2 = 0; e2 < 4; ++e2) {
            ushort_t hh[2], ll[2];
            #pragma unroll
            for (int s = 0; s < 2; ++s) {
                int q = qg * 8 + e2 * 2 + s;
                float v = 0.f;
                if (q < 27) {
                    int ci = q / 9, r = (q % 9) / 3, kw = q % 3;
                    v = pS[ci][r][2 * n + kw];
                }
                _Float16 h = (_Float16)v;
                _Float16 l = (_Float16)(v - (float)h);
                hh[s] = f16bits(h); ll[s] = f16bits(l);
            }
            uh[e2] = (unsigned)hh[0] | ((unsigned)hh[1] << 16);
            ul[e2] = (unsigned)ll[0] | ((unsigned)ll[1] << 16);
        }
        *(uint4*)&Ah[n][qg * 8] = *(uint4*)uh;
        *(uint4*)&Al[n][qg * 8] = *(uint4*)ul;
    }
    __syncthreads();

    int lane = tid & 63, w = tid >> 6;
    int la = lane & 15, lg = lane >> 4;
    int wbase = w * 64;

    float bj[4];
    f16x8 bh[4], bl[4];
    #pragma unroll
    for (int j = 0; j < 4; ++j) {
        bj[j] = bias[wbase + j * 16 + la];
        int off = ((w * 4 + j) * 64 + lane) * 8;
        bh[j] = *(const f16x8*)&WFh[off];
        bl[j] = *(const f16x8*)&WFl[off];
    }

    f16x8 ah[4], al[4];
    #pragma unroll
    for (int i = 0; i < 4; ++i) {
        ah[i] = *(const f16x8*)&Ah[i * 16 + la][lg * 8];
        al[i] = *(const f16x8*)&Al[i * 16 + la][lg * 8];
    }

    f32x4 acc[4][4];
    #pragma unroll
    for (int i = 0; i < 4; ++i)
        #pragma unroll
        for (int j = 0; j < 4; ++j) acc[i][j] = (f32x4)0.f;

    #pragma unroll
    for (int i = 0; i < 4; ++i)
        #pragma unroll
        for (int j = 0; j < 4; ++j) {
            acc[i][j] = __builtin_amdgcn_mfma_f32_16x16x32_f16(ah[i], bh[j], acc[i][j], 0, 0, 0);
            acc[i][j] = __builtin_amdgcn_mfma_f32_16x16x32_f16(al[i], bh[j], acc[i][j], 0, 0, 0);
            acc[i][j] = __builtin_amdgcn_mfma_f32_16x16x32_f16(ah[i], bl[j], acc[i][j], 0, 0, 0);
        }

    float s[4][4];
    #pragma unroll
    for (int i = 0; i < 4; ++i)
        #pragma unroll
        for (int r = 0; r < 4; ++r) s[i][r] = 0.f;

    #pragma unroll
    for (int i = 0; i < 4; ++i)
        #pragma unroll
        for (int j = 0; j < 4; ++j)
            #pragma unroll
            for (int r = 0; r < 4; ++r)
                s[i][r] += fmaxf(acc[i][j][r] + bj[j], 0.f);

    #pragma unroll
    for (int i = 0; i < 4; ++i)
        #pragma unroll
        for (int r = 0; r < 4; ++r) {
            float v = s[i][r];
            v += __shfl_xor(v, 1, 64);
            v += __shfl_xor(v, 2, 64);
            v += __shfl_xor(v, 4, 64);
            v += __shfl_xor(v, 8, 64);
            s[i][r] = v;
        }
    if (la == 0) {
        #pragma unroll
        for (int i = 0; i < 4; ++i)
            #pragma unroll
            for (int r = 0; r < 4; ++r)
                redS[w][i * 16 + lg * 4 + r] = s[i][r];
    }
    __syncthreads();
    if (tid < 64) {
        float tot = redS[0][tid] + redS[1][tid] + redS[2][tid] + redS[3][tid];
        unsigned u = __float_as_uint(tot);
        u = (u & 0x80000000u) ? ~u : (u | 0x80000000u);
        int loc = (oh & 7) * 8 + (tid & 7);
        unsigned long long key = ((unsigned long long)u << 32) | (unsigned)(63 - loc);
        #pragma unroll
        for (int off = 1; off < 8; off <<= 1) {
            unsigned long long o = shfl_xor_u64(key, off);
            key = (o > key) ? o : key;
        }
        if ((tid & 7) == 0) {
            int kr = oh >> 3, kc = (ow0 >> 3) + (tid >> 3);
            atomicMax(&pooled[b * KK + kr * 16 + kc], key);
        }
    }
}

// =====================================================================
// Select: decode pooled argmax + descriptor conv-recompute (fp32 exact).
// =====================================================================
__global__ __launch_bounds__(256) void select_kernel(
        const unsigned long long* __restrict__ pooled,
        const float* __restrict__ xA, const float* __restrict__ W,
        const float* __restrict__ bias,
        int* __restrict__ idxA,
        ushort_t* __restrict__ dFh, ushort_t* __restrict__ dFl,
        float* __restrict__ normA)
{
    __shared__ float patch[27];
    __shared__ float red[4];
    __shared__ int   sidx;

    int bk = blockIdx.x;              // b*KK + k
    int b = bk >> 8, k = bk & 255;
    int t = threadIdx.x;              // channel c

    if (t == 0) {
        unsigned long long key = pooled[bk];
        int loc = 63 - (int)(key & 0xffffffffull);
        int kr = k >> 4, kc = k & 15;
        int r = kr * 8 + (loc >> 3), c = kc * 8 + (loc & 7);
        int idx = r * HF + c;
        idxA[bk] = idx;
        sidx = idx;
    }
    __syncthreads();
    int idx = sidx;
    int oh = idx >> 7, ow = idx & 127;

    if (t < 27) {
        int ci = t / 9, kh = (t % 9) / 3, kw = t % 3;
        int ir = oh * 2 - 1 + kh, ic = ow * 2 - 1 + kw;
        float v = 0.f;
        if (ir >= 0 && ir < HIN && ic >= 0 && ic < HIN)
            v = xA[((size_t)b * CIN + ci) * HIN * HIN + (size_t)ir * HIN + ic];
        patch[t] = v;
    }
    __syncthreads();

    float v = bias[t];
    const float* w = &W[t * 27];
    #pragma unroll
    for (int q = 0; q < 27; ++q) v = fmaf(patch[q], w[q], v);
    v = fmaxf(v, 0.f);

    _Float16 h = (_Float16)v;
    _Float16 l = (_Float16)(v - (float)h);
    {
        int kt = k >> 4, la = k & 15;
        int chunk = t >> 5, lg = (t >> 3) & 3, e = t & 7;
        int off = b * DFB + dfoff(kt, chunk, lg * 16 + la) + e;
        dFh[off] = f16bits(h);
        dFl[off] = f16bits(l);
    }

    float s = v * v;
    for (int off = 32; off > 0; off >>= 1) s += __shfl_down(s, off, 64);
    if ((t & 63) == 0) red[t >> 6] = s;
    __syncthreads();
    if (t == 0) normA[bk] = red[0] + red[1] + red[2] + red[3];
}

// ---- fused-kernel helpers ----
__device__ inline void load_desc(const ushort_t* __restrict__ dFh,
                                 const ushort_t* __restrict__ dFl,
                                 int w, int chunk, int lane,
                                 f16x8* bh, f16x8* bl)
{
    #pragma unroll
    for (int jj = 0; jj < 2; ++jj) {
        int off = dfoff(w * 2 + jj, chunk, lane);
        bh[jj] = *(const f16x8*)&dFh[off];
        bl[jj] = *(const f16x8*)&dFl[off];
    }
}

__device__ inline void knn_chunk(const ushort_t* __restrict__ fH,
                                 const ushort_t* __restrict__ fL,
                                 int la, int lg, int cc,
                                 const f16x8* bh, const f16x8* bl,
                                 f32x4 (&acc)[4][2])
{
    #pragma unroll
    for (int i = 0; i < 4; ++i) {
        f16x8 ah = *(const f16x8*)&fH[swz(i * 16 + la, cc + lg * 8)];
        f16x8 al = *(const f16x8*)&fL[swz(i * 16 + la, cc + lg * 8)];
        __builtin_amdgcn_s_setprio(1);
        #pragma unroll
        for (int jj = 0; jj < 2; ++jj) {
            acc[i][jj] = __builtin_amdgcn_mfma_f32_16x16x32_f16(ah, bh[jj], acc[i][jj], 0, 0, 0);
            acc[i][jj] = __builtin_amdgcn_mfma_f32_16x16x32_f16(al, bh[jj], acc[i][jj], 0, 0, 0);
            acc[i][jj] = __builtin_amdgcn_mfma_f32_16x16x32_f16(ah, bl[jj], acc[i][jj], 0, 0, 0);
        }
        __builtin_amdgcn_s_setprio(0);
    }
}

// =====================================================================
// FUSED conv-B + kNN + (last block) both MLPs.
// 64-pixel blocks, 512 threads (8 waves), 2 blk/CU.
// =====================================================================
__global__ __launch_bounds__(512, 4) void fused_kernel(
        const float* __restrict__ xB,
        const ushort_t* __restrict__ WFh, const ushort_t* __restrict__ WFl,
        const float* __restrict__ bias,
        const ushort_t* __restrict__ dFhg, const ushort_t* __restrict__ dFlg,
        const float* __restrict__ normA, const int* __restrict__ idxA,
        unsigned long long* __restrict__ packed, unsigned* __restrict__ done,
        const float* __restrict__ W1r, const float* __restrict__ b1r,
        const float* __restrict__ W2r, const float* __restrict__ b2r,
        const float* __restrict__ W1c, const float* __restrict__ b1c,
        const float* __restrict__ W2c, const float* __restrict__ b2c,
        float* __restrict__ out)
{
    __shared__ __align__(16) char smem[2 * PX * 256 * 2];   // 65536 B
    __shared__ float redS[8][PX];
    __shared__ float nAS[KK];
    __shared__ float nBS[PX];
    __shared__ float bS[COUT];
    __shared__ unsigned isLast;
    __shared__ float mred[4][2];

    float*    pSp = (float*)smem;                            // [3][3][132] = 4752B
    ushort_t* AhP = (ushort_t*)(smem + 4752);                // [64][40] = 5120B
    ushort_t* AlP = (ushort_t*)(smem + 4752 + 5120);         // [64][40]
    ushort_t* fH  = (ushort_t*)smem;                         // [PX][256] swizzled
    ushort_t* fL  = (ushort_t*)(smem + PX * 256 * 2);        // [PX][256] swizzled

    int tile = blockIdx.x;           // 0..255 (n-tile)
    int b    = blockIdx.y;
    int oh   = tile >> 1;
    int ow0  = (tile & 1) << 6;
    const float* x = xB + (size_t)b * CIN * HIN * HIN;
    int tid = threadIdx.x;

    if (tid < KK) {
        nAS[tid] = normA[b * KK + tid];
        bS[tid]  = bias[tid];
    }

    // ---- stage input rows: 3ci x 3kh x 129 cols ----
    for (int i = tid; i < CIN * 3 * 129; i += 512) {
        int ci = i / (3 * 129);
        int r2 = i % (3 * 129);
        int kh = r2 / 129, c = r2 % 129;
        int gr = 2 * oh - 1 + kh, gc = 2 * ow0 - 1 + c;
        float v = 0.f;
        if (gr >= 0 && gr < HIN && gc >= 0 && gc < HIN)
            v = x[(size_t)ci * HIN * HIN + (size_t)gr * HIN + gc];
        pSp[ci * 396 + kh * 132 + c] = v;
    }
    __syncthreads();

    // ---- im2col ----
    {
        int n = tid >> 3, qg = tid & 7;
        ushort_t hh[4], ll[4];
        #pragma unroll
        for (int s = 0; s < 4; ++s) {
            int q = qg * 4 + s;
            float v = 0.f;
            if (q < 27) {
                int ci = q / 9, r = (q % 9) / 3, kw = q % 3;
                v = pSp[ci * 396 + r * 132 + 2 * n + kw];
            }
            _Float16 h = (_Float16)v;
            _Float16 l = (_Float16)(v - (float)h);
            hh[s] = f16bits(h); ll[s] = f16bits(l);
        }
        unsigned lo, hi;
        lo = (unsigned)hh[0] | ((unsigned)hh[1] << 16);
        hi = (unsigned)hh[2] | ((unsigned)hh[3] << 16);
        *(uint2*)&AhP[n * 40 + qg * 4] = make_uint2(lo, hi);
        lo = (unsigned)ll[0] | ((unsigned)ll[1] << 16);
        hi = (unsigned)ll[2] | ((unsigned)ll[3] << 16);
        *(uint2*)&AlP[n * 40 + qg * 4] = make_uint2(lo, hi);
    }
    __syncthreads();

    int lane = tid & 63, w = tid >> 6;     // w = 0..7
    int la = lane & 15, lg = lane >> 4;

    // ---- conv MFMA, SWAPPED ----
    f16x8 wah[2], wal[2], pbh[4], pbl[4];
    #pragma unroll
    for (int jj = 0; jj < 2; ++jj) {
        int off = ((w * 2 + jj) * 64 + lane) * 8;
        wah[jj] = *(const f16x8*)&WFh[off];
        wal[jj] = *(const f16x8*)&WFl[off];
    }
    #pragma unroll
    for (int i = 0; i < 4; ++i) {
        pbh[i] = *(const f16x8*)&AhP[(i * 16 + la) * 40 + lg * 8];
        pbl[i] = *(const f16x8*)&AlP[(i * 16 + la) * 40 + lg * 8];
    }

    f32x4 cacc[2][4];
    #pragma unroll
    for (int jj = 0; jj < 2; ++jj)
        #pragma unroll
        for (int i = 0; i < 4; ++i) cacc[jj][i] = (f32x4)0.f;

    #pragma unroll
    for (int jj = 0; jj < 2; ++jj)
        #pragma unroll
        for (int i = 0; i < 4; ++i) {
            cacc[jj][i] = __builtin_amdgcn_mfma_f32_16x16x32_f16(wah[jj], pbh[i], cacc[jj][i], 0, 0, 0);
            cacc[jj][i] = __builtin_amdgcn_mfma_f32_16x16x32_f16(wal[jj], pbh[i], cacc[jj][i], 0, 0, 0);
            cacc[jj][i] = __builtin_amdgcn_mfma_f32_16x16x32_f16(wah[jj], pbl[i], cacc[jj][i], 0, 0, 0);
        }

    __syncthreads();   // all waves done reading AhP/AlP (aliased with fH)

    // ---- epilogue: relu + f16 split into swizzled planes + sumsq ----
    float s2[4] = {0.f, 0.f, 0.f, 0.f};
    #pragma unroll
    for (int jj = 0; jj < 2; ++jj) {
        int co4 = (w * 2 + jj) * 16 + lg * 4;
        f32x4 b4 = *(const f32x4*)&bS[co4];
        int chunk = co4 >> 3;
        int within = (lg & 1) * 4;
        #pragma unroll
        for (int i = 0; i < 4; ++i) {
            int pix = i * 16 + la;
            float v0 = fmaxf(cacc[jj][i][0] + b4[0], 0.f);
            float v1 = fmaxf(cacc[jj][i][1] + b4[1], 0.f);
            float v2 = fmaxf(cacc[jj][i][2] + b4[2], 0.f);
            float v3 = fmaxf(cacc[jj][i][3] + b4[3], 0.f);
            s2[i] += v0 * v0 + v1 * v1 + v2 * v2 + v3 * v3;
            fp16v2 h01 = __builtin_amdgcn_cvt_pkrtz(v0, v1);
            fp16v2 h23 = __builtin_amdgcn_cvt_pkrtz(v2, v3);
            fp16v2 l01 = __builtin_amdgcn_cvt_pkrtz(v0 - (float)h01[0], v1 - (float)h01[1]);
            fp16v2 l23 = __builtin_amdgcn_cvt_pkrtz(v2 - (float)h23[0], v3 - (float)h23[1]);
            int base = pix * 256 + ((chunk ^ (pix & 7)) << 3) + within;
            *(uint2*)&fH[base] = make_uint2(__builtin_bit_cast(unsigned, h01),
                                            __builtin_bit_cast(unsigned, h23));
            *(uint2*)&fL[base] = make_uint2(__builtin_bit_cast(unsigned, l01),
                                            __builtin_bit_cast(unsigned, l23));
        }
    }

    // ---- early desc prefetch ----
    const ushort_t* dFh = dFhg + (size_t)b * DFB;
    const ushort_t* dFl = dFlg + (size_t)b * DFB;
    f16x8 bhA[2], blA[2], bhB[2], blB[2];
    load_desc(dFh, dFl, w, 0, lane, bhA, blA);
    load_desc(dFh, dFl, w, 1, lane, bhB, blB);

    // ---- normB ----
    #pragma unroll
    for (int i = 0; i < 4; ++i) {
        float v = s2[i];
        v += __shfl_xor(v, 16, 64);
        v += __shfl_xor(v, 32, 64);
        if (lg == 0) redS[w][i * 16 + la] = v;
    }
    __syncthreads();
    if (tid < PX) {
        float t0 = 0.f;
        #pragma unroll
        for (int p = 0; p < 8; ++p) t0 += redS[p][tid];
        nBS[tid] = t0;
    }
    __syncthreads();

    // ---- kNN: 3-pass MFMA, 2-deep desc prefetch, no barriers ----
    f32x4 acc[4][2];
    #pragma unroll
    for (int i = 0; i < 4; ++i)
        #pragma unroll
        for (int jj = 0; jj < 2; ++jj) acc[i][jj] = (f32x4)0.f;

    knn_chunk(fH, fL, la, lg, 0, bhA, blA, acc);
    load_desc(dFh, dFl, w, 2, lane, bhA, blA);
    knn_chunk(fH, fL, la, lg, 32, bhB, blB, acc);
    load_desc(dFh, dFl, w, 3, lane, bhB, blB);
    knn_chunk(fH, fL, la, lg, 64, bhA, blA, acc);
    load_desc(dFh, dFl, w, 4, lane, bhA, blA);
    knn_chunk(fH, fL, la, lg, 96, bhB, blB, acc);
    load_desc(dFh, dFl, w, 5, lane, bhB, blB);
    knn_chunk(fH, fL, la, lg, 128, bhA, blA, acc);
    load_desc(dFh, dFl, w, 6, lane, bhA, blA);
    knn_chunk(fH, fL, la, lg, 160, bhB, blB, acc);
    load_desc(dFh, dFl, w, 7, lane, bhB, blB);
    knn_chunk(fH, fL, la, lg, 192, bhA, blA, acc);
    knn_chunk(fH, fL, la, lg, 224, bhB, blB, acc);

    // ---- epilogue: dist + per-k argmin, atomicMin out ----
    float nBv[4][4];
    #pragma unroll
    for (int i = 0; i < 4; ++i) {
        f32x4 t4 = *(const f32x4*)&nBS[i * 16 + lg * 4];
        nBv[i][0] = t4[0]; nBv[i][1] = t4[1]; nBv[i][2] = t4[2]; nBv[i][3] = t4[3];
    }
    int n0 = tile * PX;
    float bd[2];
    int   bn[2];
    #pragma unroll
    for (int jj = 0; jj < 2; ++jj) {
        int kl = (w * 2 + jj) * 16 + la;
        float nAv = nAS[kl];
        float bestd = 3.4e38f;
        int   bestn = 0;
        #pragma unroll
        for (int i = 0; i < 4; ++i)
            #pragma unroll
            for (int r = 0; r < 4; ++r) {
                int n = n0 + i * 16 + lg * 4 + r;
                float d = fmaf(-2.f, acc[i][jj][r], nAv) + nBv[i][r];
                if (d < bestd) { bestd = d; bestn = n; }
            }
        #pragma unroll
        for (int off = 16; off <= 32; off <<= 1) {
            float od = __shfl_xor(bestd, off, 64);
            int   on = __shfl_xor(bestn, off, 64);
            bool take = (od < bestd) || (od == bestd && on < bestn);
            bestd = take ? od : bestd;
            bestn = take ? on : bestn;
        }
        bd[jj] = bestd; bn[jj] = bestn;
    }
    if (lg < 2) {
        float fd = (lg == 0) ? bd[0] : bd[1];
        int   fn = (lg == 0) ? bn[0] : bn[1];
        unsigned u = __float_as_uint(fd);
        u = (u & 0x80000000u) ? ~u : (u | 0x80000000u);
        unsigned long long key = ((unsigned long long)u << 32) | (unsigned)fn;
        int klw = (w * 2 + lg) * 16 + la;
        atomicMin(&packed[b * KK + klw], key);
    }

    // ---- last-block-done: run both MLPs inline ----
    if (tid == 0) {
        __threadfence();
        unsigned v = atomicAdd(done, 1u);
        isLast = (v == (unsigned)(NB * NT - 1)) ? 1u : 0u;
    }
    __syncthreads();
    if (isLast) {
        volatile const unsigned long long* pk = packed;
        float* xS = (float*)smem;            // [8 units][KK]
        for (int u2 = tid; u2 < 8 * KK; u2 += 512) {
            int unit = u2 >> 8;              // b*2 + which
            int k = u2 & 255;
            int bb = unit >> 1, which = unit & 1;
            int ia = idxA[bb * KK + k];
            int nn = (int)(pk[bb * KK + k] & 0xffffffffULL);
            int rowA = ia >> 7, colA = ia & 127;
            int rowB = nn >> 7, colB = nn & 127;
            xS[unit * KK + k] = (which == 0) ? (float)(rowB - rowA)
                                             : (float)(colA - colB);
        }
        __syncthreads();
        for (int rd = 0; rd < 2; ++rd) {
            int unit = rd * 4 + (tid >> 7);
            int t = tid & 127;
            int bb = unit >> 1, which = unit & 1;
            const float* W1 = which ? W1c : W1r;
            const float* b1 = which ? b1c : b1r;
            const float* W2 = which ? W2c : W2r;
            const float* b2 = which ? b2c : b2r;
            const float* xSu = &xS[unit * KK];
            float h = b1[t];
            for (int k = 0; k < KK; ++k) h = fmaf(xSu[k], W1[k * HID + t], h);
            h = fmaxf(h, 0.f);
            float pv = h * W2[t];
            for (int off = 32; off > 0; off >>= 1) pv += __shfl_down(pv, off, 64);
            if ((t & 63) == 0) mred[tid >> 7][t >> 6] = pv;
            __syncthreads();
            if (t == 0) out[bb * 2 + which] = mred[tid >> 7][0] + mred[tid >> 7][1] + b2[0];
            __syncthreads();
        }
    }
}

// =====================================================================
extern "C" void kernel_launch(void* const* d_in, const int* in_sizes, int n_in,
                              void* d_out, int out_size, void* d_ws, size_t ws_size,
                              hipStream_t stream)
{
    const float* xA  = (const float*)d_in[0];
    const float* xB  = (const float*)d_in[1];
    const float* Wc  = (const float*)d_in[2];
    const float* bc  = (const float*)d_in[3];
    const float* W1r = (const float*)d_in[4];
    const float* b1r = (const float*)d_in[5];
    const float* W2r = (const float*)d_in[6];
    const float* b2r = (const float*)d_in[7];
    const float* W1c = (const float*)d_in[8];
    const float* b1c = (const float*)d_in[9];
    const float* W2c = (const float*)d_in[10];
    const float* b2c = (const float*)d_in[11];
    float* out = (float*)d_out;

    char* ws = (char*)d_ws;
    unsigned long long* packed = (unsigned long long*)ws; ws += (size_t)NB * KK * 8;
    unsigned long long* pooled = (unsigned long long*)ws; ws += (size_t)NB * KK * 8;
    unsigned* done = (unsigned*)ws; ws += 256;   // padded
    int*   idxA   = (int*)ws;      ws += (size_t)NB * KK * 4;
    float* normA  = (float*)ws;    ws += (size_t)NB * KK * 4;
    ushort_t* dFh = (ushort_t*)ws; ws += (size_t)NB * DFB * 2;
    ushort_t* dFl = (ushort_t*)ws; ws += (size_t)NB * DFB * 2;
    ushort_t* WFh = (ushort_t*)ws; ws += (size_t)COUT * 32 * 2;
    ushort_t* WFl = (ushort_t*)ws; ws += (size_t)COUT * 32 * 2;

    prep_kernel  <<<1, 256, 0, stream>>>(Wc, WFh, WFl, packed, pooled, done);
    convA_kernel <<<dim3(256, NB), 256, 0, stream>>>(xA, WFh, WFl, bc, pooled);
    select_kernel<<<NB * KK, 256, 0, stream>>>(pooled, xA, Wc, bc, idxA, dFh, dFl, normA);
    fused_kernel <<<dim3(NT, NB), 512, 0, stream>>>(xB, WFh, WFl, bc, dFh, dFl,
                                                    normA, idxA, packed, done,
                                                    W1r, b1r, W2r, b2r,
                                                    W1c, b1c, W2c, b2c, out);
}

// Round 20
// 57.354 us; speedup vs baseline: 1.3567x; 1.3567x over previous
//
#include <hip/hip_runtime.h>
#include <stdint.h>

// ---- problem constants ----
constexpr int NB   = 4;      // batch
constexpr int CIN  = 3;
constexpr int HIN  = 256;
constexpr int COUT = 256;
constexpr int HF   = 128;              // feature H=W after stride-2 conv
constexpr int NF   = HF * HF;          // 16384
constexpr int KADM = 16;
constexpr int KK   = KADM * KADM;      // 256 descriptors
constexpr int HID  = 128;              // MLP hidden
constexpr int DFB  = 65536;            // desc-fragment u16s per batch
constexpr int PX   = 64;               // pixels per fused block
constexpr int NT   = NF / PX;          // 256 tiles per batch

typedef unsigned short ushort_t;
typedef __attribute__((ext_vector_type(8))) _Float16 f16x8;
typedef __attribute__((ext_vector_type(2))) __fp16   fp16v2;   // cvt_pkrtz result type
typedef __attribute__((ext_vector_type(4))) float    f32x4;

__device__ inline ushort_t f16bits(_Float16 h) { return __builtin_bit_cast(ushort_t, h); }

__device__ inline unsigned long long shfl_xor_u64(unsigned long long v, int m) {
    unsigned lo = __shfl_xor((unsigned)v, m, 64);
    unsigned hi = __shfl_xor((unsigned)(v >> 32), m, 64);
    return ((unsigned long long)hi << 32) | lo;
}

// LDS swizzle for [PX][256] f16 planes: XOR 8-f16 chunk index with pix&7.
__device__ inline int swz(int pix, int c) {
    return pix * 256 + ((((c >> 3) ^ (pix & 7)) << 3) | (c & 7));
}

// desc/weight fragment address: [kt][chunk][lane][8], kt = k>>4 (16 k-tiles)
__device__ inline int dfoff(int kt, int chunk, int lane) {
    return ((kt * 8 + chunk) * 64 + lane) * 8;
}

// =====================================================================
// Prep: split conv weights into f16 hi/lo (fragment order) + clear
// packed (+inf keys) and pooled (0 keys).
// =====================================================================
__global__ __launch_bounds__(256) void prep_kernel(
        const float* __restrict__ W, ushort_t* __restrict__ WFh, ushort_t* __restrict__ WFl,
        unsigned long long* __restrict__ packed, unsigned long long* __restrict__ pooled)
{
    int co = threadIdx.x;
    int kt = co >> 4, la = co & 15;
    #pragma unroll
    for (int q = 0; q < 32; ++q) {
        float v = (q < 27) ? W[co * 27 + q] : 0.f;
        _Float16 h = (_Float16)v;
        _Float16 l = (_Float16)(v - (float)h);
        int lg = q >> 3, e = q & 7;
        int off = (kt * 64 + lg * 16 + la) * 8 + e;
        WFh[off] = f16bits(h);
        WFl[off] = f16bits(l);
    }
    #pragma unroll
    for (int m = 0; m < NB * KK / 256; ++m) {
        packed[m * 256 + co] = ~0ull;
        pooled[m * 256 + co] = 0ull;
    }
}

// =====================================================================
// Conv-A: MFMA im2col conv + FUSED adaptive-pool argmax.
// Per row-tile: channel-sum per pixel, 8-lane group reduce per pool-col,
// atomicMax(u64 key) into pooled[b*KK + poolblock]. No resp buffer.
// Grid (256, NB), 256 threads.
// =====================================================================
__global__ __launch_bounds__(256) void convA_kernel(
        const float* __restrict__ xA,
        const ushort_t* __restrict__ WFh, const ushort_t* __restrict__ WFl,
        const float* __restrict__ bias, unsigned long long* __restrict__ pooled)
{
    __shared__ float    pS[CIN][3][132];
    __shared__ ushort_t Ah[64][40];
    __shared__ ushort_t Al[64][40];
    __shared__ float    redS[4][64];

    int tile = blockIdx.x;
    int b    = blockIdx.y;
    int oh   = tile >> 1;
    int ow0  = (tile & 1) << 6;
    const float* x = xA + (size_t)b * CIN * HIN * HIN;
    int tid = threadIdx.x;

    for (int i = tid; i < CIN * 3 * 129; i += 256) {
        int ci = i / (3 * 129);
        int r2 = i % (3 * 129);
        int kh = r2 / 129, c = r2 % 129;
        int gr = 2 * oh - 1 + kh, gc = 2 * ow0 - 1 + c;
        float v = 0.f;
        if (gr >= 0 && gr < HIN && gc >= 0 && gc < HIN)
            v = x[(size_t)ci * HIN * HIN + (size_t)gr * HIN + gc];
        pS[ci][kh][c] = v;
    }
    __syncthreads();

    {
        int n = tid >> 2, qg = tid & 3;
        unsigned uh[4], ul[4];
        #pragma unroll
        for (int e2 = 0; e2 < 4; ++e2) {
            ushort_t hh[2], ll[2];
            #pragma unroll
            for (int s = 0; s < 2; ++s) {
                int q = qg * 8 + e2 * 2 + s;
                float v = 0.f;
                if (q < 27) {
                    int ci = q / 9, r = (q % 9) / 3, kw = q % 3;
                    v = pS[ci][r][2 * n + kw];
                }
                _Float16 h = (_Float16)v;
                _Float16 l = (_Float16)(v - (float)h);
                hh[s] = f16bits(h); ll[s] = f16bits(l);
            }
            uh[e2] = (unsigned)hh[0] | ((unsigned)hh[1] << 16);
            ul[e2] = (unsigned)ll[0] | ((unsigned)ll[1] << 16);
        }
        *(uint4*)&Ah[n][qg * 8] = *(uint4*)uh;
        *(uint4*)&Al[n][qg * 8] = *(uint4*)ul;
    }
    __syncthreads();

    int lane = tid & 63, w = tid >> 6;
    int la = lane & 15, lg = lane >> 4;
    int wbase = w * 64;

    float bj[4];
    f16x8 bh[4], bl[4];
    #pragma unroll
    for (int j = 0; j < 4; ++j) {
        bj[j] = bias[wbase + j * 16 + la];
        int off = ((w * 4 + j) * 64 + lane) * 8;
        bh[j] = *(const f16x8*)&WFh[off];
        bl[j] = *(const f16x8*)&WFl[off];
    }

    f16x8 ah[4], al[4];
    #pragma unroll
    for (int i = 0; i < 4; ++i) {
        ah[i] = *(const f16x8*)&Ah[i * 16 + la][lg * 8];
        al[i] = *(const f16x8*)&Al[i * 16 + la][lg * 8];
    }

    f32x4 acc[4][4];
    #pragma unroll
    for (int i = 0; i < 4; ++i)
        #pragma unroll
        for (int j = 0; j < 4; ++j) acc[i][j] = (f32x4)0.f;

    #pragma unroll
    for (int i = 0; i < 4; ++i)
        #pragma unroll
        for (int j = 0; j < 4; ++j) {
            acc[i][j] = __builtin_amdgcn_mfma_f32_16x16x32_f16(ah[i], bh[j], acc[i][j], 0, 0, 0);
            acc[i][j] = __builtin_amdgcn_mfma_f32_16x16x32_f16(al[i], bh[j], acc[i][j], 0, 0, 0);
            acc[i][j] = __builtin_amdgcn_mfma_f32_16x16x32_f16(ah[i], bl[j], acc[i][j], 0, 0, 0);
        }

    float s[4][4];
    #pragma unroll
    for (int i = 0; i < 4; ++i)
        #pragma unroll
        for (int r = 0; r < 4; ++r) s[i][r] = 0.f;

    #pragma unroll
    for (int i = 0; i < 4; ++i)
        #pragma unroll
        for (int j = 0; j < 4; ++j)
            #pragma unroll
            for (int r = 0; r < 4; ++r)
                s[i][r] += fmaxf(acc[i][j][r] + bj[j], 0.f);

    #pragma unroll
    for (int i = 0; i < 4; ++i)
        #pragma unroll
        for (int r = 0; r < 4; ++r) {
            float v = s[i][r];
            v += __shfl_xor(v, 1, 64);
            v += __shfl_xor(v, 2, 64);
            v += __shfl_xor(v, 4, 64);
            v += __shfl_xor(v, 8, 64);
            s[i][r] = v;
        }
    if (la == 0) {
        #pragma unroll
        for (int i = 0; i < 4; ++i)
            #pragma unroll
            for (int r = 0; r < 4; ++r)
                redS[w][i * 16 + lg * 4 + r] = s[i][r];
    }
    __syncthreads();
    if (tid < 64) {
        float tot = redS[0][tid] + redS[1][tid] + redS[2][tid] + redS[3][tid];
        // pooled argmax key: sortable(resp)<<32 | (63 - loc); max => largest
        // resp, tie => smallest loc (jnp.argmax first-occurrence).
        unsigned u = __float_as_uint(tot);
        u = (u & 0x80000000u) ? ~u : (u | 0x80000000u);
        int loc = (oh & 7) * 8 + (tid & 7);
        unsigned long long key = ((unsigned long long)u << 32) | (unsigned)(63 - loc);
        #pragma unroll
        for (int off = 1; off < 8; off <<= 1) {
            unsigned long long o = shfl_xor_u64(key, off);
            key = (o > key) ? o : key;
        }
        if ((tid & 7) == 0) {
            int kr = oh >> 3, kc = (ow0 >> 3) + (tid >> 3);
            atomicMax(&pooled[b * KK + kr * 16 + kc], key);
        }
    }
}

// =====================================================================
// Select: decode pooled argmax + descriptor conv-recompute (fp32 exact).
// Writes desc in fragment order dF[b][kt][chunk][lane][8].
// =====================================================================
__global__ __launch_bounds__(256) void select_kernel(
        const unsigned long long* __restrict__ pooled,
        const float* __restrict__ xA, const float* __restrict__ W,
        const float* __restrict__ bias,
        int* __restrict__ idxA,
        ushort_t* __restrict__ dFh, ushort_t* __restrict__ dFl,
        float* __restrict__ normA)
{
    __shared__ float patch[27];
    __shared__ float red[4];
    __shared__ int   sidx;

    int bk = blockIdx.x;              // b*KK + k
    int b = bk >> 8, k = bk & 255;
    int t = threadIdx.x;              // channel c

    if (t == 0) {
        unsigned long long key = pooled[bk];
        int loc = 63 - (int)(key & 0xffffffffull);
        int kr = k >> 4, kc = k & 15;
        int r = kr * 8 + (loc >> 3), c = kc * 8 + (loc & 7);
        int idx = r * HF + c;
        idxA[bk] = idx;
        sidx = idx;
    }
    __syncthreads();
    int idx = sidx;
    int oh = idx >> 7, ow = idx & 127;

    if (t < 27) {
        int ci = t / 9, kh = (t % 9) / 3, kw = t % 3;
        int ir = oh * 2 - 1 + kh, ic = ow * 2 - 1 + kw;
        float v = 0.f;
        if (ir >= 0 && ir < HIN && ic >= 0 && ic < HIN)
            v = xA[((size_t)b * CIN + ci) * HIN * HIN + (size_t)ir * HIN + ic];
        patch[t] = v;
    }
    __syncthreads();

    float v = bias[t];
    const float* w = &W[t * 27];
    #pragma unroll
    for (int q = 0; q < 27; ++q) v = fmaf(patch[q], w[q], v);
    v = fmaxf(v, 0.f);

    _Float16 h = (_Float16)v;
    _Float16 l = (_Float16)(v - (float)h);
    {
        int kt = k >> 4, la = k & 15;
        int chunk = t >> 5, lg = (t >> 3) & 3, e = t & 7;
        int off = b * DFB + dfoff(kt, chunk, lg * 16 + la) + e;
        dFh[off] = f16bits(h);
        dFl[off] = f16bits(l);
    }

    float s = v * v;
    for (int off = 32; off > 0; off >>= 1) s += __shfl_down(s, off, 64);
    if ((t & 63) == 0) red[t >> 6] = s;
    __syncthreads();
    if (t == 0) normA[bk] = red[0] + red[1] + red[2] + red[3];
}

// ---- fused-kernel helpers ----
__device__ inline void load_desc(const ushort_t* __restrict__ dFh,
                                 const ushort_t* __restrict__ dFl,
                                 int w, int chunk, int lane,
                                 f16x8* bh, f16x8* bl)
{
    #pragma unroll
    for (int jj = 0; jj < 2; ++jj) {
        int off = dfoff(w * 2 + jj, chunk, lane);
        bh[jj] = *(const f16x8*)&dFh[off];
        bl[jj] = *(const f16x8*)&dFl[off];
    }
}

__device__ inline void knn_chunk(const ushort_t* __restrict__ fH,
                                 const ushort_t* __restrict__ fL,
                                 int la, int lg, int cc,
                                 const f16x8* bh, const f16x8* bl,
                                 f32x4 (&acc)[4][2])
{
    #pragma unroll
    for (int i = 0; i < 4; ++i) {
        f16x8 ah = *(const f16x8*)&fH[swz(i * 16 + la, cc + lg * 8)];
        f16x8 al = *(const f16x8*)&fL[swz(i * 16 + la, cc + lg * 8)];
        __builtin_amdgcn_s_setprio(1);
        #pragma unroll
        for (int jj = 0; jj < 2; ++jj) {
            acc[i][jj] = __builtin_amdgcn_mfma_f32_16x16x32_f16(ah, bh[jj], acc[i][jj], 0, 0, 0);
            acc[i][jj] = __builtin_amdgcn_mfma_f32_16x16x32_f16(al, bh[jj], acc[i][jj], 0, 0, 0);
            acc[i][jj] = __builtin_amdgcn_mfma_f32_16x16x32_f16(ah, bl[jj], acc[i][jj], 0, 0, 0);
        }
        __builtin_amdgcn_s_setprio(0);
    }
}

// =====================================================================
// FUSED conv-B + kNN, 64-pixel blocks, 512 threads (8 waves), 2 blk/CU
// (= 16 waves/CU). Wave w owns k-tiles {2w, 2w+1} (32 k).
// atomicMin winner into packed[b][k].
// =====================================================================
__global__ __launch_bounds__(512, 4) void fused_kernel(
        const float* __restrict__ xB,
        const ushort_t* __restrict__ WFh, const ushort_t* __restrict__ WFl,
        const float* __restrict__ bias,
        const ushort_t* __restrict__ dFhg, const ushort_t* __restrict__ dFlg,
        const float* __restrict__ normA,
        unsigned long long* __restrict__ packed)
{
    __shared__ __align__(16) char smem[2 * PX * 256 * 2];   // 65536 B
    __shared__ float redS[8][PX];
    __shared__ float nAS[KK];
    __shared__ float nBS[PX];
    __shared__ float bS[COUT];

    float*    pSp = (float*)smem;                            // [3][3][132] = 4752B
    ushort_t* AhP = (ushort_t*)(smem + 4752);                // [64][40] = 5120B
    ushort_t* AlP = (ushort_t*)(smem + 4752 + 5120);         // [64][40]
    ushort_t* fH  = (ushort_t*)smem;                         // [PX][256] swizzled
    ushort_t* fL  = (ushort_t*)(smem + PX * 256 * 2);        // [PX][256] swizzled

    int tile = blockIdx.x;           // 0..255 (n-tile)
    int b    = blockIdx.y;
    int oh   = tile >> 1;
    int ow0  = (tile & 1) << 6;
    const float* x = xB + (size_t)b * CIN * HIN * HIN;
    int tid = threadIdx.x;

    if (tid < KK) {
        nAS[tid] = normA[b * KK + tid];
        bS[tid]  = bias[tid];
    }

    // ---- stage input rows: 3ci x 3kh x 129 cols ----
    for (int i = tid; i < CIN * 3 * 129; i += 512) {
        int ci = i / (3 * 129);
        int r2 = i % (3 * 129);
        int kh = r2 / 129, c = r2 % 129;
        int gr = 2 * oh - 1 + kh, gc = 2 * ow0 - 1 + c;
        float v = 0.f;
        if (gr >= 0 && gr < HIN && gc >= 0 && gc < HIN)
            v = x[(size_t)ci * HIN * HIN + (size_t)gr * HIN + gc];
        pSp[ci * 396 + kh * 132 + c] = v;
    }
    __syncthreads();

    // ---- im2col: n = tid>>3 (0..63), qg = tid&7 -> q = qg*4+s ----
    {
        int n = tid >> 3, qg = tid & 7;
        ushort_t hh[4], ll[4];
        #pragma unroll
        for (int s = 0; s < 4; ++s) {
            int q = qg * 4 + s;
            float v = 0.f;
            if (q < 27) {
                int ci = q / 9, r = (q % 9) / 3, kw = q % 3;
                v = pSp[ci * 396 + r * 132 + 2 * n + kw];
            }
            _Float16 h = (_Float16)v;
            _Float16 l = (_Float16)(v - (float)h);
            hh[s] = f16bits(h); ll[s] = f16bits(l);
        }
        unsigned lo, hi;
        lo = (unsigned)hh[0] | ((unsigned)hh[1] << 16);
        hi = (unsigned)hh[2] | ((unsigned)hh[3] << 16);
        *(uint2*)&AhP[n * 40 + qg * 4] = make_uint2(lo, hi);
        lo = (unsigned)ll[0] | ((unsigned)ll[1] << 16);
        hi = (unsigned)ll[2] | ((unsigned)ll[3] << 16);
        *(uint2*)&AlP[n * 40 + qg * 4] = make_uint2(lo, hi);
    }
    __syncthreads();

    int lane = tid & 63, w = tid >> 6;     // w = 0..7
    int la = lane & 15, lg = lane >> 4;

    // ---- conv MFMA, SWAPPED: A=weights (M = 2 kt ch-tiles), B=im2col (N = 4 i px-tiles)
    f16x8 wah[2], wal[2], pbh[4], pbl[4];
    #pragma unroll
    for (int jj = 0; jj < 2; ++jj) {
        int off = ((w * 2 + jj) * 64 + lane) * 8;
        wah[jj] = *(const f16x8*)&WFh[off];
        wal[jj] = *(const f16x8*)&WFl[off];
    }
    #pragma unroll
    for (int i = 0; i < 4; ++i) {
        pbh[i] = *(const f16x8*)&AhP[(i * 16 + la) * 40 + lg * 8];
        pbl[i] = *(const f16x8*)&AlP[(i * 16 + la) * 40 + lg * 8];
    }

    f32x4 cacc[2][4];
    #pragma unroll
    for (int jj = 0; jj < 2; ++jj)
        #pragma unroll
        for (int i = 0; i < 4; ++i) cacc[jj][i] = (f32x4)0.f;

    #pragma unroll
    for (int jj = 0; jj < 2; ++jj)
        #pragma unroll
        for (int i = 0; i < 4; ++i) {
            cacc[jj][i] = __builtin_amdgcn_mfma_f32_16x16x32_f16(wah[jj], pbh[i], cacc[jj][i], 0, 0, 0);
            cacc[jj][i] = __builtin_amdgcn_mfma_f32_16x16x32_f16(wal[jj], pbh[i], cacc[jj][i], 0, 0, 0);
            cacc[jj][i] = __builtin_amdgcn_mfma_f32_16x16x32_f16(wah[jj], pbl[i], cacc[jj][i], 0, 0, 0);
        }

    __syncthreads();   // all waves done reading AhP/AlP (aliased with fH)

    // ---- epilogue: D lane = pixel i*16+la, channels (2w+jj)*16 + lg*4+{0..3}
    float s2[4] = {0.f, 0.f, 0.f, 0.f};
    #pragma unroll
    for (int jj = 0; jj < 2; ++jj) {
        int co4 = (w * 2 + jj) * 16 + lg * 4;
        f32x4 b4 = *(const f32x4*)&bS[co4];
        int chunk = co4 >> 3;
        int within = (lg & 1) * 4;
        #pragma unroll
        for (int i = 0; i < 4; ++i) {
            int pix = i * 16 + la;
            float v0 = fmaxf(cacc[jj][i][0] + b4[0], 0.f);
            float v1 = fmaxf(cacc[jj][i][1] + b4[1], 0.f);
            float v2 = fmaxf(cacc[jj][i][2] + b4[2], 0.f);
            float v3 = fmaxf(cacc[jj][i][3] + b4[3], 0.f);
            s2[i] += v0 * v0 + v1 * v1 + v2 * v2 + v3 * v3;
            fp16v2 h01 = __builtin_amdgcn_cvt_pkrtz(v0, v1);
            fp16v2 h23 = __builtin_amdgcn_cvt_pkrtz(v2, v3);
            fp16v2 l01 = __builtin_amdgcn_cvt_pkrtz(v0 - (float)h01[0], v1 - (float)h01[1]);
            fp16v2 l23 = __builtin_amdgcn_cvt_pkrtz(v2 - (float)h23[0], v3 - (float)h23[1]);
            int base = pix * 256 + ((chunk ^ (pix & 7)) << 3) + within;
            *(uint2*)&fH[base] = make_uint2(__builtin_bit_cast(unsigned, h01),
                                            __builtin_bit_cast(unsigned, h23));
            *(uint2*)&fL[base] = make_uint2(__builtin_bit_cast(unsigned, l01),
                                            __builtin_bit_cast(unsigned, l23));
        }
    }

    // ---- early desc prefetch (cacc dead; loads fly under barrier/reduce) ----
    const ushort_t* dFh = dFhg + (size_t)b * DFB;
    const ushort_t* dFl = dFlg + (size_t)b * DFB;
    f16x8 bhA[2], blA[2], bhB[2], blB[2];
    load_desc(dFh, dFl, w, 0, lane, bhA, blA);
    load_desc(dFh, dFl, w, 1, lane, bhB, blB);

    // ---- normB: reduce s2 over lg lanes (same pixel la), then waves ----
    #pragma unroll
    for (int i = 0; i < 4; ++i) {
        float v = s2[i];
        v += __shfl_xor(v, 16, 64);
        v += __shfl_xor(v, 32, 64);
        if (lg == 0) redS[w][i * 16 + la] = v;
    }
    __syncthreads();
    if (tid < PX) {
        float t0 = 0.f;
        #pragma unroll
        for (int p = 0; p < 8; ++p) t0 += redS[p][tid];
        nBS[tid] = t0;
    }
    __syncthreads();

    // ---- kNN: 3-pass MFMA, 2-deep desc prefetch, no barriers ----
    f32x4 acc[4][2];
    #pragma unroll
    for (int i = 0; i < 4; ++i)
        #pragma unroll
        for (int jj = 0; jj < 2; ++jj) acc[i][jj] = (f32x4)0.f;

    knn_chunk(fH, fL, la, lg, 0, bhA, blA, acc);
    load_desc(dFh, dFl, w, 2, lane, bhA, blA);
    knn_chunk(fH, fL, la, lg, 32, bhB, blB, acc);
    load_desc(dFh, dFl, w, 3, lane, bhB, blB);
    knn_chunk(fH, fL, la, lg, 64, bhA, blA, acc);
    load_desc(dFh, dFl, w, 4, lane, bhA, blA);
    knn_chunk(fH, fL, la, lg, 96, bhB, blB, acc);
    load_desc(dFh, dFl, w, 5, lane, bhB, blB);
    knn_chunk(fH, fL, la, lg, 128, bhA, blA, acc);
    load_desc(dFh, dFl, w, 6, lane, bhA, blA);
    knn_chunk(fH, fL, la, lg, 160, bhB, blB, acc);
    load_desc(dFh, dFl, w, 7, lane, bhB, blB);
    knn_chunk(fH, fL, la, lg, 192, bhA, blA, acc);
    knn_chunk(fH, fL, la, lg, 224, bhB, blB, acc);

    // ---- epilogue: dist + per-k argmin (float compares), atomicMin out ----
    float nBv[4][4];
    #pragma unroll
    for (int i = 0; i < 4; ++i) {
        f32x4 t4 = *(const f32x4*)&nBS[i * 16 + lg * 4];
        nBv[i][0] = t4[0]; nBv[i][1] = t4[1]; nBv[i][2] = t4[2]; nBv[i][3] = t4[3];
    }
    int n0 = tile * PX;
    float bd[2];
    int   bn[2];
    #pragma unroll
    for (int jj = 0; jj < 2; ++jj) {
        int kl = (w * 2 + jj) * 16 + la;
        float nAv = nAS[kl];
        float bestd = 3.4e38f;
        int   bestn = 0;
        #pragma unroll
        for (int i = 0; i < 4; ++i)       // ascending n within thread
            #pragma unroll
            for (int r = 0; r < 4; ++r) {
                int n = n0 + i * 16 + lg * 4 + r;
                float d = fmaf(-2.f, acc[i][jj][r], nAv) + nBv[i][r];
                if (d < bestd) { bestd = d; bestn = n; }   // strict: first min kept
            }
        #pragma unroll
        for (int off = 16; off <= 32; off <<= 1) {
            float od = __shfl_xor(bestd, off, 64);
            int   on = __shfl_xor(bestn, off, 64);
            bool take = (od < bestd) || (od == bestd && on < bestn);
            bestd = take ? od : bestd;
            bestn = take ? on : bestn;
        }
        bd[jj] = bestd; bn[jj] = bestn;
    }
    // lanes lg=0 handle jj=0, lg=1 handle jj=1
    if (lg < 2) {
        float fd = (lg == 0) ? bd[0] : bd[1];
        int   fn = (lg == 0) ? bn[0] : bn[1];
        unsigned u = __float_as_uint(fd);
        u = (u & 0x80000000u) ? ~u : (u | 0x80000000u);
        unsigned long long key = ((unsigned long long)u << 32) | (unsigned)fn;
        int klw = (w * 2 + lg) * 16 + la;
        atomicMin(&packed[b * KK + klw], key);
    }
}

// =====================================================================
// Two tiny MLPs: x(256) -> 128 relu -> 1. block per (b, which), 128 threads.
// =====================================================================
__global__ __launch_bounds__(128) void mlp_kernel(
        const int* __restrict__ idxA, const unsigned long long* __restrict__ packed,
        const float* __restrict__ W1r, const float* __restrict__ b1r,
        const float* __restrict__ W2r, const float* __restrict__ b2r,
        const float* __restrict__ W1c, const float* __restrict__ b1c,
        const float* __restrict__ W2c, const float* __restrict__ b2c,
        float* __restrict__ out)
{
    __shared__ float xS[KK];
    __shared__ float red[2];
    int blk = blockIdx.x;            // b*2 + which
    int b = blk >> 1, which = blk & 1;
    int t = threadIdx.x;             // 0..127

    for (int k = t; k < KK; k += 128) {
        int ia = idxA[b * KK + k];
        int nn = (int)(packed[b * KK + k] & 0xffffffffULL);
        int rowA = ia >> 7, colA = ia & 127;
        int rowB = nn >> 7, colB = nn & 127;
        xS[k] = (which == 0) ? (float)(rowB - rowA) : (float)(colA - colB);
    }
    __syncthreads();

    const float* W1 = which ? W1c : W1r;
    const float* b1 = which ? b1c : b1r;
    const float* W2 = which ? W2c : W2r;
    const float* b2 = which ? b2c : b2r;

    float h = b1[t];
    for (int k = 0; k < KK; ++k) h = fmaf(xS[k], W1[k * HID + t], h);
    h = fmaxf(h, 0.f);
    float pv = h * W2[t];
    for (int off = 32; off > 0; off >>= 1) pv += __shfl_down(pv, off, 64);
    if ((t & 63) == 0) red[t >> 6] = pv;
    __syncthreads();
    if (t == 0) out[b * 2 + which] = red[0] + red[1] + b2[0];
}

// =====================================================================
extern "C" void kernel_launch(void* const* d_in, const int* in_sizes, int n_in,
                              void* d_out, int out_size, void* d_ws, size_t ws_size,
                              hipStream_t stream)
{
    const float* xA  = (const float*)d_in[0];
    const float* xB  = (const float*)d_in[1];
    const float* Wc  = (const float*)d_in[2];
    const float* bc  = (const float*)d_in[3];
    const float* W1r = (const float*)d_in[4];
    const float* b1r = (const float*)d_in[5];
    const float* W2r = (const float*)d_in[6];
    const float* b2r = (const float*)d_in[7];
    const float* W1c = (const float*)d_in[8];
    const float* b1c = (const float*)d_in[9];
    const float* W2c = (const float*)d_in[10];
    const float* b2c = (const float*)d_in[11];
    float* out = (float*)d_out;

    char* ws = (char*)d_ws;
    unsigned long long* packed = (unsigned long long*)ws; ws += (size_t)NB * KK * 8;
    unsigned long long* pooled = (unsigned long long*)ws; ws += (size_t)NB * KK * 8;
    int*   idxA   = (int*)ws;      ws += (size_t)NB * KK * 4;
    float* normA  = (float*)ws;    ws += (size_t)NB * KK * 4;
    ushort_t* dFh = (ushort_t*)ws; ws += (size_t)NB * DFB * 2;
    ushort_t* dFl = (ushort_t*)ws; ws += (size_t)NB * DFB * 2;
    ushort_t* WFh = (ushort_t*)ws; ws += (size_t)COUT * 32 * 2;
    ushort_t* WFl = (ushort_t*)ws; ws += (size_t)COUT * 32 * 2;

    prep_kernel  <<<1, 256, 0, stream>>>(Wc, WFh, WFl, packed, pooled);
    convA_kernel <<<dim3(256, NB), 256, 0, stream>>>(xA, WFh, WFl, bc, pooled);
    select_kernel<<<NB * KK, 256, 0, stream>>>(pooled, xA, Wc, bc, idxA, dFh, dFl, normA);
    fused_kernel <<<dim3(NT, NB), 512, 0, stream>>>(xB, WFh, WFl, bc, dFh, dFl,
                                                    normA, packed);
    mlp_kernel   <<<8, 128, 0, stream>>>(idxA, packed,
                                         W1r, b1r, W2r, b2r,
                                         W1c, b1c, W2c, b2c, out);
}